// Round 8
// baseline (187.941 us; speedup 1.0000x reference)
//
#include <hip/hip_runtime.h>
#include <hip/hip_bf16.h>

#define T_TOK 8192
#define DDIM  512
#define FDIM  1024
#define NEXP  8
#define KTOP  2
#define NSLOT (T_TOK * KTOP)       // 16384
#define MAX_ROWS 17408             // 16384 + 8*127 rounded up to 128
#define MAX_T128 136               // MAX_ROWS / 128

// prep kernel block ranges
#define NB_CAST 512                // 8192*512/8 elems / 1024 thr/blk / 8 per thr
#define NB_T    4096               // 8 experts * 512 32x32 tiles
#define PREP_BLOCKS (1 + NB_CAST + NB_T + NB_T)   // 8705

typedef __attribute__((ext_vector_type(8))) __bf16 bf16x8;
typedef __attribute__((ext_vector_type(4))) __bf16 bf16x4;
typedef __attribute__((ext_vector_type(4))) float  f32x4;
typedef __attribute__((ext_vector_type(8))) unsigned short u16x8;

typedef __attribute__((address_space(1))) const unsigned int* gp1;
typedef __attribute__((address_space(3))) unsigned int*       lp3;
#define GL2LDS(g, l) __builtin_amdgcn_global_load_lds((gp1)(const void*)(g), (lp3)(void*)(l), 16, 0, 0)

// meta int layout: [16] ntiles128, [17:25) expert row offsets
// Contract (proven): inputs fp32, idx int32, output compared as bf16.

__device__ __forceinline__ float gelu_fast(float x){
    // 0.5*x*(1+tanh(u)) == x * sigmoid(2u)
    float u = 0.7978845608028654f * (x + 0.044715f * x * x * x);
    return x / (1.0f + __expf(-2.0f * u));
}

__device__ __forceinline__ unsigned short f2bf(float v){
    __hip_bfloat16 b = __float2bfloat16(v);
    return *(unsigned short*)&b;
}

// ---- Fused prep: bucket (block 0) + cast x (512 blocks) + transpose W1/W2.
__global__ __launch_bounds__(1024) void prep_kernel(
    const float* __restrict__ x, const int* __restrict__ idx,
    const float* __restrict__ W1, const float* __restrict__ W2,
    unsigned short* __restrict__ xbf,
    unsigned short* __restrict__ w1t, unsigned short* __restrict__ w2t,
    int* __restrict__ meta, int2* __restrict__ map,
    int* __restrict__ list, int* __restrict__ slot2row)
{
    __shared__ unsigned long long sA[1024], sB[1024];   // bucket scan, 16 KB
    __shared__ unsigned short tile[32][33];             // transpose, 2.1 KB
    const int b   = blockIdx.x;
    const int tid = threadIdx.x;

    if (b == 0){
        // ---- bucket: 16 slots/thread, 16-bit-packed dual-u64 scan ----
        const int base = tid * 16;
        int mye[16];
        unsigned long long a = 0, bb = 0;
        #pragma unroll
        for (int i = 0; i < 16; i++){
            int e = idx[base + i] & 7;
            mye[i] = e;
            unsigned long long one = 1ull << (16 * (e & 3));
            if (e < 4) a += one; else bb += one;
        }
        sA[tid] = a; sB[tid] = bb;
        __syncthreads();
        for (int off = 1; off < 1024; off <<= 1){
            unsigned long long ta = 0, tb = 0;
            if (tid >= off){ ta = sA[tid - off]; tb = sB[tid - off]; }
            __syncthreads();
            sA[tid] += ta; sB[tid] += tb;
            __syncthreads();
        }
        const unsigned long long iA = sA[tid],  iB = sB[tid];
        const unsigned long long tA = sA[1023], tB = sB[1023];

        int cnt[NEXP], pad[NEXP], off_e[NEXP], tc[NEXP + 1];
        tc[0] = 0;
        int o = 0;
        #pragma unroll
        for (int e = 0; e < NEXP; e++){
            unsigned long long src = (e < 4) ? tA : tB;
            cnt[e] = (int)((src >> (16 * (e & 3))) & 0xffffull);
            pad[e] = (cnt[e] + 127) & ~127;
            off_e[e] = o; o += pad[e];
            tc[e + 1] = tc[e] + (pad[e] >> 7);
        }
        const int nrows = o, nt = tc[NEXP];

        if (tid == 0) meta[16] = nt;
        if (tid < NEXP) meta[17 + tid] = off_e[tid];
        if (tid < nt){
            int e = 0;
            while (tid >= tc[e + 1]) e++;
            map[tid] = make_int2(e, off_e[e] + (tid - tc[e]) * 128);
        }

        int run[NEXP];
        #pragma unroll
        for (int e = 0; e < NEXP; e++){
            unsigned long long isrc = (e < 4) ? iA : iB;
            unsigned long long csrc = (e < 4) ? a  : bb;
            int incl = (int)((isrc >> (16 * (e & 3))) & 0xffffull);
            int ce   = (int)((csrc >> (16 * (e & 3))) & 0xffffull);
            run[e] = off_e[e] + incl - ce;
        }
        #pragma unroll
        for (int i = 0; i < 16; i++){
            int e = mye[i];
            int gg = run[e]++;
            list[gg] = (base + i) >> 1;      // row -> token (K=2)
            slot2row[base + i] = gg;         // slot -> row (combine)
        }
        for (int p = tid; p < nrows; p += 1024){
            #pragma unroll
            for (int e = 0; e < NEXP; e++){
                if (p >= off_e[e] + cnt[e] && p < off_e[e] + pad[e]) list[p] = 0;
            }
        }
    } else if (b < 1 + NB_CAST){
        // ---- cast x -> bf16, 8 elems/thread ----
        int i = (b - 1) * 1024 + tid;          // < 524288
        const float4* s = (const float4*)x;
        float4 va = s[2 * i];
        float4 vb = s[2 * i + 1];
        u16x8 ov;
        ov[0] = f2bf(va.x); ov[1] = f2bf(va.y); ov[2] = f2bf(va.z); ov[3] = f2bf(va.w);
        ov[4] = f2bf(vb.x); ov[5] = f2bf(vb.y); ov[6] = f2bf(vb.z); ov[7] = f2bf(vb.w);
        *(u16x8*)(xbf + (size_t)i * 8) = ov;
    } else {
        // ---- transpose_cast: [E][R][C] fp32 -> [E][C][R] bf16, 32x32 tiles ----
        int blk = b - (1 + NB_CAST);
        const float* src; unsigned short* dst; int R, C, cpb_shift, cpb_mask;
        if (blk < NB_T){ src = W1; dst = w1t; R = DDIM; C = FDIM; cpb_shift = 5; cpb_mask = 31; }
        else           { src = W2; dst = w2t; R = FDIM; C = DDIM; cpb_shift = 4; cpb_mask = 15; blk -= NB_T; }
        int e   = blk >> 9;            // 512 tiles per expert
        int rem = blk & 511;
        int rb  = rem >> cpb_shift, cb = rem & cpb_mask;
        int r0 = rb * 32, c0 = cb * 32;
        int tx = tid & 31, ty = tid >> 5;   // (32,32)
        const float* sf = src + (size_t)e * R * C;
        unsigned short* d = dst + (size_t)e * R * C;
        tile[ty][tx] = f2bf(sf[(size_t)(r0 + ty) * C + c0 + tx]);
        __syncthreads();
        d[(size_t)(c0 + ty) * R + r0 + tx] = tile[tx][ty];
    }
}

// ---- Counted-vmcnt sync (T4): wait only for the PREVIOUS stage's 8 loads,
// leaving the just-issued 8 in flight across the barrier. Raw s_barrier with
// asm memory-clobber before and sched_barrier(0) after (rule #18 pinning).
#define WAIT8_BAR() do {                                             \
    asm volatile("s_waitcnt vmcnt(8)" ::: "memory");                 \
    __builtin_amdgcn_s_barrier();                                    \
    __builtin_amdgcn_sched_barrier(0);                               \
} while (0)
#define WAIT0_BAR() do {                                             \
    asm volatile("s_waitcnt vmcnt(0)" ::: "memory");                 \
    __builtin_amdgcn_s_barrier();                                    \
    __builtin_amdgcn_sched_barrier(0);                               \
} while (0)
#define POST_BAR() do {                                              \
    __builtin_amdgcn_sched_barrier(0);                               \
    __builtin_amdgcn_s_barrier();                                    \
    __builtin_amdgcn_sched_barrier(0);                               \
} while (0)

// ---- GEMM1: h[row, F] = gelu(xbf[tok(row)] @ W1t[e]^T + b1[e]) ----
// R2's proven geometry (128x128 tile, BK=64, split K-panels [ks=2][128][32],
// 64 B row stride) + T4 counted-vmcnt double-buffer (64 KB LDS, 2 blocks/CU):
// per step: STAGE(next buf) -> vmcnt(8) (prev stage done, new one flies) ->
// barrier -> 32 MFMA -> barrier. Static buffer indexing via manual 2x unroll.
__global__ __launch_bounds__(256, 2) void gemm1_kernel(
    const unsigned short* __restrict__ x,
    const unsigned short* __restrict__ w1t,
    const float* __restrict__ b1,
    const int* __restrict__ meta,
    const int2* __restrict__ map,
    const int* __restrict__ list,
    unsigned short* __restrict__ h)
{
    const int ntiles = meta[16];
    const int nwg = ntiles * (FDIM / 128);            // 8 n-tiles per row-tile
    int id = blockIdx.y * gridDim.x + blockIdx.x;
    if (id >= nwg) return;
    // bijective XCD swizzle (m204 variant)
    int q = nwg >> 3, r = nwg & 7;
    int xcd = id & 7, rank = id >> 3;
    int swz = (xcd < r) ? (xcd * (q + 1) + rank)
                        : (r * (q + 1) + (xcd - r) * q + rank);
    const int tile = swz >> 3;                        // / (FDIM/128)
    const int n0 = (swz & 7) * 128;
    int2 em = map[tile];
    const int e = em.x, grow0 = em.y;

    __shared__ __align__(16) unsigned short As0[2 * 128 * 32];   // 16 KB each
    __shared__ __align__(16) unsigned short As1[2 * 128 * 32];
    __shared__ __align__(16) unsigned short Bs0[2 * 128 * 32];
    __shared__ __align__(16) unsigned short Bs1[2 * 128 * 32];

    const int tid  = threadIdx.x;
    const int wave = tid >> 6;
    const int lane = tid & 63;
    const int rl   = lane >> 2;         // row within 16-row group
    const int kq   = lane & 3;          // 16B k-octet within 32-elem panel

    const int row0 = wave * 16 + rl;        // 0..63
    const int row1 = 64 + wave * 16 + rl;   // 64..127

    const unsigned short* pA0 = x + (size_t)list[grow0 + row0] * DDIM + kq * 8;
    const unsigned short* pA1 = x + (size_t)list[grow0 + row1] * DDIM + kq * 8;
    const unsigned short* pB0 = w1t + ((size_t)e * FDIM + n0 + row0) * DDIM + kq * 8;
    const unsigned short* pB1 = w1t + ((size_t)e * FDIM + n0 + row1) * DDIM + kq * 8;

    const int quad = lane >> 4, lrow = lane & 15;
    const int wr = (wave >> 1) * 64;    // wave row offset
    const int wc = (wave & 1) * 64;     // wave col offset

#define STG(AS, BS, kk) do {                                          \
        char* la_ = (char*)(AS) + wave * 1024;                        \
        char* lb_ = (char*)(BS) + wave * 1024;                        \
        GL2LDS(pA0 + (kk),      la_);          GL2LDS(pA1 + (kk),      la_ + 4096);  \
        GL2LDS(pA0 + (kk) + 32, la_ + 8192);   GL2LDS(pA1 + (kk) + 32, la_ + 12288); \
        GL2LDS(pB0 + (kk),      lb_);          GL2LDS(pB1 + (kk),      lb_ + 4096);  \
        GL2LDS(pB0 + (kk) + 32, lb_ + 8192);   GL2LDS(pB1 + (kk) + 32, lb_ + 12288); \
    } while (0)

#define CMP(AS, BS) do {                                              \
        bf16x8 a_[4][2], b_[4][2];                                    \
        _Pragma("unroll")                                             \
        for (int i = 0; i < 4; i++){                                  \
            _Pragma("unroll")                                         \
            for (int ks = 0; ks < 2; ks++){                           \
                a_[i][ks] = *(const bf16x8*)&(AS)[ks * 4096 + (wr + i * 16 + lrow) * 32 + quad * 8]; \
                b_[i][ks] = *(const bf16x8*)&(BS)[ks * 4096 + (wc + i * 16 + lrow) * 32 + quad * 8]; \
            }                                                         \
        }                                                             \
        _Pragma("unroll")                                             \
        for (int i = 0; i < 4; i++){                                  \
            _Pragma("unroll")                                         \
            for (int j = 0; j < 4; j++){                              \
                acc[i][j] = __builtin_amdgcn_mfma_f32_16x16x32_bf16(a_[i][0], b_[j][0], acc[i][j], 0, 0, 0); \
                acc[i][j] = __builtin_amdgcn_mfma_f32_16x16x32_bf16(a_[i][1], b_[j][1], acc[i][j], 0, 0, 0); \
            }                                                         \
        }                                                             \
    } while (0)

    f32x4 acc[4][4];
    #pragma unroll
    for (int i = 0; i < 4; i++)
        #pragma unroll
        for (int j = 0; j < 4; j++) acc[i][j] = (f32x4)0.0f;

    STG(As0, Bs0, 0);
    const int NK = DDIM / 64;   // 8 (even)
    for (int t = 0; t < NK; t += 2){
        STG(As1, Bs1, (t + 1) * 64);        // prefetch odd step
        WAIT8_BAR();                        // wait even-step stage only
        CMP(As0, Bs0);
        POST_BAR();                         // protect As0 before re-stage
        if (t + 2 < NK){
            STG(As0, Bs0, (t + 2) * 64);    // prefetch next even step
            WAIT8_BAR();
        } else {
            WAIT0_BAR();
        }
        CMP(As1, Bs1);
        POST_BAR();
    }
#undef STG
#undef CMP

    #pragma unroll
    for (int j = 0; j < 4; j++){
        int cn = n0 + wc + j * 16 + lrow;
        float bias = b1[e * FDIM + cn];
        #pragma unroll
        for (int i = 0; i < 4; i++){
            #pragma unroll
            for (int rr = 0; rr < 4; rr++){
                int gr = grow0 + wr + i * 16 + quad * 4 + rr;
                h[(size_t)gr * FDIM + cn] = f2bf(gelu_fast(acc[i][j][rr] + bias));
            }
        }
    }
}

// ---- GEMM2: y[row, D] = h[row] @ W2t[e]^T + b2[e] ----
// Same counted-vmcnt structure, K=FDIM. W2t layout [E][D][F] bf16.
__global__ __launch_bounds__(256, 2) void gemm2_kernel(
    const unsigned short* __restrict__ h,
    const unsigned short* __restrict__ w2t,
    const float* __restrict__ b2,
    const int* __restrict__ meta,
    const int2* __restrict__ map,
    unsigned short* __restrict__ y)
{
    const int ntiles = meta[16];
    const int nwg = ntiles * (DDIM / 128);            // 4 n-tiles per row-tile
    int id = blockIdx.y * gridDim.x + blockIdx.x;
    if (id >= nwg) return;
    int q = nwg >> 3, r = nwg & 7;
    int xcd = id & 7, rank = id >> 3;
    int swz = (xcd < r) ? (xcd * (q + 1) + rank)
                        : (r * (q + 1) + (xcd - r) * q + rank);
    const int tile = swz >> 2;                        // / (DDIM/128)
    const int n0 = (swz & 3) * 128;
    int2 em = map[tile];
    const int e = em.x, grow0 = em.y;

    __shared__ __align__(16) unsigned short As0[2 * 128 * 32];
    __shared__ __align__(16) unsigned short As1[2 * 128 * 32];
    __shared__ __align__(16) unsigned short Bs0[2 * 128 * 32];
    __shared__ __align__(16) unsigned short Bs1[2 * 128 * 32];

    const int tid  = threadIdx.x;
    const int wave = tid >> 6;
    const int lane = tid & 63;
    const int rl   = lane >> 2;
    const int kq   = lane & 3;

    const int row0 = wave * 16 + rl;
    const int row1 = 64 + wave * 16 + rl;

    const unsigned short* pA0 = h + (size_t)(grow0 + row0) * FDIM + kq * 8;
    const unsigned short* pA1 = h + (size_t)(grow0 + row1) * FDIM + kq * 8;
    const unsigned short* pB0 = w2t + ((size_t)e * DDIM + n0 + row0) * FDIM + kq * 8;
    const unsigned short* pB1 = w2t + ((size_t)e * DDIM + n0 + row1) * FDIM + kq * 8;

    const int quad = lane >> 4, lrow = lane & 15;
    const int wr = (wave >> 1) * 64;
    const int wc = (wave & 1) * 64;

#define STG(AS, BS, kk) do {                                          \
        char* la_ = (char*)(AS) + wave * 1024;                        \
        char* lb_ = (char*)(BS) + wave * 1024;                        \
        GL2LDS(pA0 + (kk),      la_);          GL2LDS(pA1 + (kk),      la_ + 4096);  \
        GL2LDS(pA0 + (kk) + 32, la_ + 8192);   GL2LDS(pA1 + (kk) + 32, la_ + 12288); \
        GL2LDS(pB0 + (kk),      lb_);          GL2LDS(pB1 + (kk),      lb_ + 4096);  \
        GL2LDS(pB0 + (kk) + 32, lb_ + 8192);   GL2LDS(pB1 + (kk) + 32, lb_ + 12288); \
    } while (0)

#define CMP(AS, BS) do {                                              \
        bf16x8 a_[4][2], b_[4][2];                                    \
        _Pragma("unroll")                                             \
        for (int i = 0; i < 4; i++){                                  \
            _Pragma("unroll")                                         \
            for (int ks = 0; ks < 2; ks++){                           \
                a_[i][ks] = *(const bf16x8*)&(AS)[ks * 4096 + (wr + i * 16 + lrow) * 32 + quad * 8]; \
                b_[i][ks] = *(const bf16x8*)&(BS)[ks * 4096 + (wc + i * 16 + lrow) * 32 + quad * 8]; \
            }                                                         \
        }                                                             \
        _Pragma("unroll")                                             \
        for (int i = 0; i < 4; i++){                                  \
            _Pragma("unroll")                                         \
            for (int j = 0; j < 4; j++){                              \
                acc[i][j] = __builtin_amdgcn_mfma_f32_16x16x32_bf16(a_[i][0], b_[j][0], acc[i][j], 0, 0, 0); \
                acc[i][j] = __builtin_amdgcn_mfma_f32_16x16x32_bf16(a_[i][1], b_[j][1], acc[i][j], 0, 0, 0); \
            }                                                         \
        }                                                             \
    } while (0)

    f32x4 acc[4][4];
    #pragma unroll
    for (int i = 0; i < 4; i++)
        #pragma unroll
        for (int j = 0; j < 4; j++) acc[i][j] = (f32x4)0.0f;

    STG(As0, Bs0, 0);
    const int NK = FDIM / 64;   // 16 (even)
    for (int t = 0; t < NK; t += 2){
        STG(As1, Bs1, (t + 1) * 64);
        WAIT8_BAR();
        CMP(As0, Bs0);
        POST_BAR();
        if (t + 2 < NK){
            STG(As0, Bs0, (t + 2) * 64);
            WAIT8_BAR();
        } else {
            WAIT0_BAR();
        }
        CMP(As1, Bs1);
        POST_BAR();
    }
#undef STG
#undef CMP

    #pragma unroll
    for (int j = 0; j < 4; j++){
        int cn = n0 + wc + j * 16 + lrow;
        float bias = b2[e * DDIM + cn];
        #pragma unroll
        for (int i = 0; i < 4; i++){
            #pragma unroll
            for (int rr = 0; rr < 4; rr++){
                int gr = grow0 + wr + i * 16 + quad * 4 + rr;
                y[(size_t)gr * DDIM + cn] = f2bf(acc[i][j][rr] + bias);
            }
        }
    }
}

// out[t, :] = wk[2t] * y[row(2t), :] + wk[2t+1] * y[row(2t+1), :]
__global__ void combine_kernel(const unsigned short* __restrict__ y,
                               const int* __restrict__ slot2row,
                               const float* __restrict__ wk,
                               float* __restrict__ out){
    int g = blockIdx.x * blockDim.x + threadIdx.x;   // over T_TOK * DDIM / 4
    int t = g >> 7, seg = g & 127;
    int ra = slot2row[2 * t], rb = slot2row[2 * t + 1];
    float wa = wk[2 * t];
    float wb = wk[2 * t + 1];
    bf16x4 ya = *(const bf16x4*)(y + (size_t)ra * DDIM + seg * 4);
    bf16x4 yb = *(const bf16x4*)(y + (size_t)rb * DDIM + seg * 4);
    float4 o;
    o.x = wa * (float)ya[0] + wb * (float)yb[0];
    o.y = wa * (float)ya[1] + wb * (float)yb[1];
    o.z = wa * (float)ya[2] + wb * (float)yb[2];
    o.w = wa * (float)ya[3] + wb * (float)yb[3];
    *(float4*)(out + (size_t)t * DDIM + seg * 4) = o;
}

extern "C" void kernel_launch(void* const* d_in, const int* in_sizes, int n_in,
                              void* d_out, int out_size, void* d_ws, size_t ws_size,
                              hipStream_t stream){
    const float* x   = (const float*)d_in[0];
    const int*   idx = (const int*)d_in[1];
    const float* wk  = (const float*)d_in[2];
    const float* W1  = (const float*)d_in[3];
    const float* b1  = (const float*)d_in[4];
    const float* W2  = (const float*)d_in[5];
    const float* b2  = (const float*)d_in[6];
    float* out = (float*)d_out;

    char* ws = (char*)d_ws;
    int*   meta     = (int*)ws;                               // 512 B
    int2*  map      = (int2*)(ws + 512);                      // up to 136*8 B
    int*   list     = (int*)(ws + 4096);                      // 69,632 B (row->token)
    int*   slot2row = (int*)(ws + 81920);                     // 65,536 B (slot->row)
    unsigned short* xbf = (unsigned short*)(ws + 262144);     // 8,388,608 B [T][D]
    unsigned short* w1t = (unsigned short*)(ws + 8650752);    // 8,388,608 B [E][F][D]
    unsigned short* w2t = (unsigned short*)(ws + 17039360);   // 8,388,608 B [E][D][F]
    unsigned short* h   = (unsigned short*)(ws + 25427968);   // 35,651,584 B [MAX_ROWS][F]
    unsigned short* y   = (unsigned short*)(ws + 61079552);   // 17,825,792 B [MAX_ROWS][D]
    if (ws_size < 78905344u) return;   // tripwire -> zero output signature

    prep_kernel<<<PREP_BLOCKS, 1024, 0, stream>>>(
        x, idx, W1, W2, xbf, w1t, w2t, meta, map, list, slot2row);

    gemm1_kernel<<<dim3(FDIM / 128, MAX_T128), 256, 0, stream>>>(
        xbf, w1t, b1, meta, map, list, h);

    gemm2_kernel<<<dim3(DDIM / 128, MAX_T128), 256, 0, stream>>>(
        h, w2t, b2, meta, map, y);

    combine_kernel<<<(T_TOK * DDIM / 4) / 256, 256, 0, stream>>>(y, slot2row, wk, out);
}

// Round 9
// 178.609 us; speedup vs baseline: 1.0523x; 1.0523x over previous
//
#include <hip/hip_runtime.h>
#include <hip/hip_bf16.h>

#define T_TOK 8192
#define DDIM  512
#define FDIM  1024
#define NEXP  8
#define KTOP  2
#define NSLOT (T_TOK * KTOP)       // 16384
#define MAX_ROWS 17408             // 16384 + 8*127 rounded up to 128
#define MAX_T128 136               // MAX_ROWS / 128

// prep kernel block ranges
#define NB_CAST 512                // 8192*512/8 elems / 1024 thr/blk / 8 per thr
#define NB_T    4096               // 8 experts * 512 32x32 tiles
#define PREP_BLOCKS (1 + NB_CAST + NB_T + NB_T)   // 8705

typedef __attribute__((ext_vector_type(8))) __bf16 bf16x8;
typedef __attribute__((ext_vector_type(4))) __bf16 bf16x4;
typedef __attribute__((ext_vector_type(4))) float  f32x4;
typedef __attribute__((ext_vector_type(8))) unsigned short u16x8;

typedef __attribute__((address_space(1))) const unsigned int* gp1;
typedef __attribute__((address_space(3))) unsigned int*       lp3;
#define GL2LDS(g, l) __builtin_amdgcn_global_load_lds((gp1)(const void*)(g), (lp3)(void*)(l), 16, 0, 0)

// meta int layout: [16] ntiles128, [17:25) expert row offsets
// Contract (proven): inputs fp32, idx int32, output compared as bf16.

__device__ __forceinline__ float gelu_fast(float x){
    // 0.5*x*(1+tanh(u)) == x * sigmoid(2u)
    float u = 0.7978845608028654f * (x + 0.044715f * x * x * x);
    return x / (1.0f + __expf(-2.0f * u));
}

__device__ __forceinline__ unsigned short f2bf(float v){
    __hip_bfloat16 b = __float2bfloat16(v);
    return *(unsigned short*)&b;
}

// ---- Fused prep: bucket (block 0) + cast x (512 blocks) + transpose W1/W2.
__global__ __launch_bounds__(1024) void prep_kernel(
    const float* __restrict__ x, const int* __restrict__ idx,
    const float* __restrict__ W1, const float* __restrict__ W2,
    unsigned short* __restrict__ xbf,
    unsigned short* __restrict__ w1t, unsigned short* __restrict__ w2t,
    int* __restrict__ meta, int2* __restrict__ map,
    int* __restrict__ list, int* __restrict__ slot2row)
{
    __shared__ unsigned long long sA[1024], sB[1024];   // bucket scan, 16 KB
    __shared__ unsigned short tile[32][33];             // transpose, 2.1 KB
    const int b   = blockIdx.x;
    const int tid = threadIdx.x;

    if (b == 0){
        // ---- bucket: 16 slots/thread, 16-bit-packed dual-u64 scan ----
        const int base = tid * 16;
        int mye[16];
        unsigned long long a = 0, bb = 0;
        #pragma unroll
        for (int i = 0; i < 16; i++){
            int e = idx[base + i] & 7;
            mye[i] = e;
            unsigned long long one = 1ull << (16 * (e & 3));
            if (e < 4) a += one; else bb += one;
        }
        sA[tid] = a; sB[tid] = bb;
        __syncthreads();
        for (int off = 1; off < 1024; off <<= 1){
            unsigned long long ta = 0, tb = 0;
            if (tid >= off){ ta = sA[tid - off]; tb = sB[tid - off]; }
            __syncthreads();
            sA[tid] += ta; sB[tid] += tb;
            __syncthreads();
        }
        const unsigned long long iA = sA[tid],  iB = sB[tid];
        const unsigned long long tA = sA[1023], tB = sB[1023];

        int cnt[NEXP], pad[NEXP], off_e[NEXP], tc[NEXP + 1];
        tc[0] = 0;
        int o = 0;
        #pragma unroll
        for (int e = 0; e < NEXP; e++){
            unsigned long long src = (e < 4) ? tA : tB;
            cnt[e] = (int)((src >> (16 * (e & 3))) & 0xffffull);
            pad[e] = (cnt[e] + 127) & ~127;
            off_e[e] = o; o += pad[e];
            tc[e + 1] = tc[e] + (pad[e] >> 7);
        }
        const int nrows = o, nt = tc[NEXP];

        if (tid == 0) meta[16] = nt;
        if (tid < NEXP) meta[17 + tid] = off_e[tid];
        if (tid < nt){
            int e = 0;
            while (tid >= tc[e + 1]) e++;
            map[tid] = make_int2(e, off_e[e] + (tid - tc[e]) * 128);
        }

        int run[NEXP];
        #pragma unroll
        for (int e = 0; e < NEXP; e++){
            unsigned long long isrc = (e < 4) ? iA : iB;
            unsigned long long csrc = (e < 4) ? a  : bb;
            int incl = (int)((isrc >> (16 * (e & 3))) & 0xffffull);
            int ce   = (int)((csrc >> (16 * (e & 3))) & 0xffffull);
            run[e] = off_e[e] + incl - ce;
        }
        #pragma unroll
        for (int i = 0; i < 16; i++){
            int e = mye[i];
            int gg = run[e]++;
            list[gg] = (base + i) >> 1;      // row -> token (K=2)
            slot2row[base + i] = gg;         // slot -> row (combine)
        }
        for (int p = tid; p < nrows; p += 1024){
            #pragma unroll
            for (int e = 0; e < NEXP; e++){
                if (p >= off_e[e] + cnt[e] && p < off_e[e] + pad[e]) list[p] = 0;
            }
        }
    } else if (b < 1 + NB_CAST){
        // ---- cast x -> bf16, 8 elems/thread ----
        int i = (b - 1) * 1024 + tid;          // < 524288
        const float4* s = (const float4*)x;
        float4 va = s[2 * i];
        float4 vb = s[2 * i + 1];
        u16x8 ov;
        ov[0] = f2bf(va.x); ov[1] = f2bf(va.y); ov[2] = f2bf(va.z); ov[3] = f2bf(va.w);
        ov[4] = f2bf(vb.x); ov[5] = f2bf(vb.y); ov[6] = f2bf(vb.z); ov[7] = f2bf(vb.w);
        *(u16x8*)(xbf + (size_t)i * 8) = ov;
    } else {
        // ---- transpose_cast: [E][R][C] fp32 -> [E][C][R] bf16, 32x32 tiles ----
        int blk = b - (1 + NB_CAST);
        const float* src; unsigned short* dst; int R, C, cpb_shift, cpb_mask;
        if (blk < NB_T){ src = W1; dst = w1t; R = DDIM; C = FDIM; cpb_shift = 5; cpb_mask = 31; }
        else           { src = W2; dst = w2t; R = FDIM; C = DDIM; cpb_shift = 4; cpb_mask = 15; blk -= NB_T; }
        int e   = blk >> 9;            // 512 tiles per expert
        int rem = blk & 511;
        int rb  = rem >> cpb_shift, cb = rem & cpb_mask;
        int r0 = rb * 32, c0 = cb * 32;
        int tx = tid & 31, ty = tid >> 5;   // (32,32)
        const float* sf = src + (size_t)e * R * C;
        unsigned short* d = dst + (size_t)e * R * C;
        tile[ty][tx] = f2bf(sf[(size_t)(r0 + ty) * C + c0 + tx]);
        __syncthreads();
        d[(size_t)(c0 + ty) * R + r0 + tx] = tile[tx][ty];
    }
}

// ---- GEMM1: h[row, F] = gelu(xbf[tok(row)] @ W1t[e]^T + b1[e]) ----
// R2/R7-proven structure: 128x128 tile, BK=64, split K-panels [ks=2][128][32]
// (64 B row stride), single-buffered 32 KB, plain __syncthreads. Explicit
// pipelines (R3 dbuf64K, R6 BK32-dbuf, R8 counted-vmcnt) all regressed:
// 2-barrier 128-tile regime relies on implicit multi-block overlap (m114).
__global__ __launch_bounds__(256, 2) void gemm1_kernel(
    const unsigned short* __restrict__ x,
    const unsigned short* __restrict__ w1t,
    const float* __restrict__ b1,
    const int* __restrict__ meta,
    const int2* __restrict__ map,
    const int* __restrict__ list,
    unsigned short* __restrict__ h)
{
    const int ntiles = meta[16];
    const int nwg = ntiles * (FDIM / 128);            // 8 n-tiles per row-tile
    int id = blockIdx.y * gridDim.x + blockIdx.x;
    if (id >= nwg) return;
    // bijective XCD swizzle (m204 variant)
    int q = nwg >> 3, r = nwg & 7;
    int xcd = id & 7, rank = id >> 3;
    int swz = (xcd < r) ? (xcd * (q + 1) + rank)
                        : (r * (q + 1) + (xcd - r) * q + rank);
    const int tile = swz >> 3;                        // / (FDIM/128)
    const int n0 = (swz & 7) * 128;
    int2 em = map[tile];
    const int e = em.x, grow0 = em.y;

    __shared__ __align__(16) unsigned short As[2 * 128 * 32];   // 16 KB [ks][row][32]
    __shared__ __align__(16) unsigned short Bs[2 * 128 * 32];   // 16 KB

    const int tid  = threadIdx.x;
    const int wave = tid >> 6;
    const int lane = tid & 63;
    const int rl   = lane >> 2;         // row within 16-row group
    const int kq   = lane & 3;          // 16B k-octet within 32-elem panel

    const int row0 = wave * 16 + rl;        // 0..63
    const int row1 = 64 + wave * 16 + rl;   // 64..127

    const unsigned short* pA0 = x + (size_t)list[grow0 + row0] * DDIM + kq * 8;
    const unsigned short* pA1 = x + (size_t)list[grow0 + row1] * DDIM + kq * 8;
    const unsigned short* pB0 = w1t + ((size_t)e * FDIM + n0 + row0) * DDIM + kq * 8;
    const unsigned short* pB1 = w1t + ((size_t)e * FDIM + n0 + row1) * DDIM + kq * 8;

    char* lA = (char*)As + wave * 1024;
    char* lB = (char*)Bs + wave * 1024;

    const int quad = lane >> 4, lrow = lane & 15;
    const int wr = (wave >> 1) * 64;    // wave row offset
    const int wc = (wave & 1) * 64;     // wave col offset

    f32x4 acc[4][4];
    #pragma unroll
    for (int i = 0; i < 4; i++)
        #pragma unroll
        for (int j = 0; j < 4; j++) acc[i][j] = (f32x4)0.0f;

    for (int kk = 0; kk < DDIM; kk += 64){
        __syncthreads();
        GL2LDS(pA0 + kk,      lA);              // ks=0, rows 0..63
        GL2LDS(pA1 + kk,      lA + 4096);       // ks=0, rows 64..127
        GL2LDS(pA0 + kk + 32, lA + 8192);       // ks=1, rows 0..63
        GL2LDS(pA1 + kk + 32, lA + 12288);      // ks=1, rows 64..127
        GL2LDS(pB0 + kk,      lB);
        GL2LDS(pB1 + kk,      lB + 4096);
        GL2LDS(pB0 + kk + 32, lB + 8192);
        GL2LDS(pB1 + kk + 32, lB + 12288);
        __syncthreads();
        bf16x8 a[4][2], b[4][2];
        #pragma unroll
        for (int i = 0; i < 4; i++){
            #pragma unroll
            for (int ks = 0; ks < 2; ks++){
                a[i][ks] = *(const bf16x8*)&As[ks * 4096 + (wr + i * 16 + lrow) * 32 + quad * 8];
                b[i][ks] = *(const bf16x8*)&Bs[ks * 4096 + (wc + i * 16 + lrow) * 32 + quad * 8];
            }
        }
        #pragma unroll
        for (int i = 0; i < 4; i++){
            #pragma unroll
            for (int j = 0; j < 4; j++){
                acc[i][j] = __builtin_amdgcn_mfma_f32_16x16x32_bf16(a[i][0], b[j][0], acc[i][j], 0, 0, 0);
                acc[i][j] = __builtin_amdgcn_mfma_f32_16x16x32_bf16(a[i][1], b[j][1], acc[i][j], 0, 0, 0);
            }
        }
    }

    #pragma unroll
    for (int j = 0; j < 4; j++){
        int cn = n0 + wc + j * 16 + lrow;
        float bias = b1[e * FDIM + cn];
        #pragma unroll
        for (int i = 0; i < 4; i++){
            #pragma unroll
            for (int rr = 0; rr < 4; rr++){
                int gr = grow0 + wr + i * 16 + quad * 4 + rr;
                h[(size_t)gr * FDIM + cn] = f2bf(gelu_fast(acc[i][j][rr] + bias));
            }
        }
    }
}

// ---- GEMM2: y[row, D] = h[row] @ W2t[e]^T + b2[e] ----
// Same proven inner structure, but 128x64 tiles: nwg = ntiles*8 = 1088 blocks
// (was 544 at 128x128 -> only ~2.1 blocks/CU, grid-starved; gemm1's 1088
// blocks give ~4.25/CU and hide the staging drain). B-tile LDS [ks=2][64][32]
// = 8 KB, block LDS 24 KB, acc[4][2]. W2t layout [E][D][F] bf16.
__global__ __launch_bounds__(256, 2) void gemm2_kernel(
    const unsigned short* __restrict__ h,
    const unsigned short* __restrict__ w2t,
    const float* __restrict__ b2,
    const int* __restrict__ meta,
    const int2* __restrict__ map,
    unsigned short* __restrict__ y)
{
    const int ntiles = meta[16];
    const int nwg = ntiles * (DDIM / 64);             // 8 n-tiles per row-tile
    int id = blockIdx.y * gridDim.x + blockIdx.x;
    if (id >= nwg) return;
    int q = nwg >> 3, r = nwg & 7;
    int xcd = id & 7, rank = id >> 3;
    int swz = (xcd < r) ? (xcd * (q + 1) + rank)
                        : (r * (q + 1) + (xcd - r) * q + rank);
    const int tile = swz >> 3;                        // / (DDIM/64)
    const int n0 = (swz & 7) * 64;
    int2 em = map[tile];
    const int e = em.x, grow0 = em.y;

    __shared__ __align__(16) unsigned short As[2 * 128 * 32];   // 16 KB
    __shared__ __align__(16) unsigned short Bs[2 * 64 * 32];    // 8 KB

    const int tid  = threadIdx.x;
    const int wave = tid >> 6;
    const int lane = tid & 63;
    const int rl   = lane >> 2;
    const int kq   = lane & 3;

    const int row0 = wave * 16 + rl;        // 0..63
    const int row1 = 64 + wave * 16 + rl;   // 64..127

    const unsigned short* pA0 = h + (size_t)(grow0 + row0) * FDIM + kq * 8;
    const unsigned short* pA1 = h + (size_t)(grow0 + row1) * FDIM + kq * 8;
    const unsigned short* pB0 = w2t + ((size_t)e * DDIM + n0 + row0) * FDIM + kq * 8;

    char* lA = (char*)As + wave * 1024;
    char* lB = (char*)Bs + wave * 1024;

    const int quad = lane >> 4, lrow = lane & 15;
    const int wr = (wave >> 1) * 64;    // wave row offset (0/64)
    const int wc = (wave & 1) * 32;     // wave col offset (0/32)

    f32x4 acc[4][2];
    #pragma unroll
    for (int i = 0; i < 4; i++)
        #pragma unroll
        for (int j = 0; j < 2; j++) acc[i][j] = (f32x4)0.0f;

    for (int kk = 0; kk < FDIM; kk += 64){
        __syncthreads();
        GL2LDS(pA0 + kk,      lA);              // A ks=0, rows 0..63
        GL2LDS(pA1 + kk,      lA + 4096);       // A ks=0, rows 64..127
        GL2LDS(pA0 + kk + 32, lA + 8192);       // A ks=1, rows 0..63
        GL2LDS(pA1 + kk + 32, lA + 12288);      // A ks=1, rows 64..127
        GL2LDS(pB0 + kk,      lB);              // B ks=0, rows 0..63
        GL2LDS(pB0 + kk + 32, lB + 4096);       // B ks=1, rows 0..63
        __syncthreads();
        bf16x8 a[4][2], b[2][2];
        #pragma unroll
        for (int i = 0; i < 4; i++){
            #pragma unroll
            for (int ks = 0; ks < 2; ks++)
                a[i][ks] = *(const bf16x8*)&As[ks * 4096 + (wr + i * 16 + lrow) * 32 + quad * 8];
        }
        #pragma unroll
        for (int j = 0; j < 2; j++){
            #pragma unroll
            for (int ks = 0; ks < 2; ks++)
                b[j][ks] = *(const bf16x8*)&Bs[ks * 2048 + (wc + j * 16 + lrow) * 32 + quad * 8];
        }
        #pragma unroll
        for (int i = 0; i < 4; i++){
            #pragma unroll
            for (int j = 0; j < 2; j++){
                acc[i][j] = __builtin_amdgcn_mfma_f32_16x16x32_bf16(a[i][0], b[j][0], acc[i][j], 0, 0, 0);
                acc[i][j] = __builtin_amdgcn_mfma_f32_16x16x32_bf16(a[i][1], b[j][1], acc[i][j], 0, 0, 0);
            }
        }
    }

    #pragma unroll
    for (int j = 0; j < 2; j++){
        int cn = n0 + wc + j * 16 + lrow;
        float bias = b2[e * DDIM + cn];
        #pragma unroll
        for (int i = 0; i < 4; i++){
            #pragma unroll
            for (int rr = 0; rr < 4; rr++){
                int gr = grow0 + wr + i * 16 + quad * 4 + rr;
                y[(size_t)gr * DDIM + cn] = f2bf(acc[i][j][rr] + bias);
            }
        }
    }
}

// out[t, :] = wk[2t] * y[row(2t), :] + wk[2t+1] * y[row(2t+1), :]
__global__ void combine_kernel(const unsigned short* __restrict__ y,
                               const int* __restrict__ slot2row,
                               const float* __restrict__ wk,
                               float* __restrict__ out){
    int g = blockIdx.x * blockDim.x + threadIdx.x;   // over T_TOK * DDIM / 4
    int t = g >> 7, seg = g & 127;
    int ra = slot2row[2 * t], rb = slot2row[2 * t + 1];
    float wa = wk[2 * t];
    float wb = wk[2 * t + 1];
    bf16x4 ya = *(const bf16x4*)(y + (size_t)ra * DDIM + seg * 4);
    bf16x4 yb = *(const bf16x4*)(y + (size_t)rb * DDIM + seg * 4);
    float4 o;
    o.x = wa * (float)ya[0] + wb * (float)yb[0];
    o.y = wa * (float)ya[1] + wb * (float)yb[1];
    o.z = wa * (float)ya[2] + wb * (float)yb[2];
    o.w = wa * (float)ya[3] + wb * (float)yb[3];
    *(float4*)(out + (size_t)t * DDIM + seg * 4) = o;
}

extern "C" void kernel_launch(void* const* d_in, const int* in_sizes, int n_in,
                              void* d_out, int out_size, void* d_ws, size_t ws_size,
                              hipStream_t stream){
    const float* x   = (const float*)d_in[0];
    const int*   idx = (const int*)d_in[1];
    const float* wk  = (const float*)d_in[2];
    const float* W1  = (const float*)d_in[3];
    const float* b1  = (const float*)d_in[4];
    const float* W2  = (const float*)d_in[5];
    const float* b2  = (const float*)d_in[6];
    float* out = (float*)d_out;

    char* ws = (char*)d_ws;
    int*   meta     = (int*)ws;                               // 512 B
    int2*  map      = (int2*)(ws + 512);                      // up to 136*8 B
    int*   list     = (int*)(ws + 4096);                      // 69,632 B (row->token)
    int*   slot2row = (int*)(ws + 81920);                     // 65,536 B (slot->row)
    unsigned short* xbf = (unsigned short*)(ws + 262144);     // 8,388,608 B [T][D]
    unsigned short* w1t = (unsigned short*)(ws + 8650752);    // 8,388,608 B [E][F][D]
    unsigned short* w2t = (unsigned short*)(ws + 17039360);   // 8,388,608 B [E][D][F]
    unsigned short* h   = (unsigned short*)(ws + 25427968);   // 35,651,584 B [MAX_ROWS][F]
    unsigned short* y   = (unsigned short*)(ws + 61079552);   // 17,825,792 B [MAX_ROWS][D]
    if (ws_size < 78905344u) return;   // tripwire -> zero output signature

    prep_kernel<<<PREP_BLOCKS, 1024, 0, stream>>>(
        x, idx, W1, W2, xbf, w1t, w2t, meta, map, list, slot2row);

    gemm1_kernel<<<dim3(FDIM / 128, MAX_T128), 256, 0, stream>>>(
        xbf, w1t, b1, meta, map, list, h);

    gemm2_kernel<<<dim3(DDIM / 64, MAX_T128), 256, 0, stream>>>(
        h, w2t, b2, meta, map, y);

    combine_kernel<<<(T_TOK * DDIM / 4) / 256, 256, 0, stream>>>(y, slot2row, wk, out);
}

// Round 10
// 177.036 us; speedup vs baseline: 1.0616x; 1.0089x over previous
//
#include <hip/hip_runtime.h>
#include <hip/hip_bf16.h>

#define T_TOK 8192
#define DDIM  512
#define FDIM  1024
#define NEXP  8
#define KTOP  2
#define NSLOT (T_TOK * KTOP)       // 16384
#define MAX_ROWS 17408             // 16384 + 8*127 rounded up to 128
#define MAX_T128 136               // MAX_ROWS / 128

// prep kernel block ranges
#define NB_CAST 512                // 8192*512/8 elems / 1024 thr/blk / 8 per thr
#define NB_T    4096               // 8 experts * 512 32x32 tiles
#define PREP_BLOCKS (1 + NB_CAST + NB_T + NB_T)   // 8705

typedef __attribute__((ext_vector_type(8))) __bf16 bf16x8;
typedef __attribute__((ext_vector_type(4))) __bf16 bf16x4;
typedef __attribute__((ext_vector_type(4))) float  f32x4;
typedef __attribute__((ext_vector_type(8))) unsigned short u16x8;

typedef __attribute__((address_space(1))) const unsigned int* gp1;
typedef __attribute__((address_space(3))) unsigned int*       lp3;
#define GL2LDS(g, l) __builtin_amdgcn_global_load_lds((gp1)(const void*)(g), (lp3)(void*)(l), 16, 0, 0)

// meta int layout: [16] ntiles128, [17:25) expert row offsets
// Contract (proven): inputs fp32, idx int32, output compared as bf16.

__device__ __forceinline__ float gelu_fast(float x){
    // 0.5*x*(1+tanh(u)) == x * sigmoid(2u)
    float u = 0.7978845608028654f * (x + 0.044715f * x * x * x);
    return x / (1.0f + __expf(-2.0f * u));
}

__device__ __forceinline__ unsigned short f2bf(float v){
    __hip_bfloat16 b = __float2bfloat16(v);
    return *(unsigned short*)&b;
}

// ---- Fused prep: bucket (block 0) + cast x (512 blocks) + transpose W1/W2.
__global__ __launch_bounds__(1024) void prep_kernel(
    const float* __restrict__ x, const int* __restrict__ idx,
    const float* __restrict__ W1, const float* __restrict__ W2,
    unsigned short* __restrict__ xbf,
    unsigned short* __restrict__ w1t, unsigned short* __restrict__ w2t,
    int* __restrict__ meta, int2* __restrict__ map,
    int* __restrict__ list, int* __restrict__ slot2row)
{
    __shared__ unsigned long long sA[1024], sB[1024];   // bucket scan, 16 KB
    __shared__ unsigned short tile[32][33];             // transpose, 2.1 KB
    const int b   = blockIdx.x;
    const int tid = threadIdx.x;

    if (b == 0){
        // ---- bucket: 16 slots/thread, 16-bit-packed dual-u64 scan ----
        const int base = tid * 16;
        int mye[16];
        unsigned long long a = 0, bb = 0;
        #pragma unroll
        for (int i = 0; i < 16; i++){
            int e = idx[base + i] & 7;
            mye[i] = e;
            unsigned long long one = 1ull << (16 * (e & 3));
            if (e < 4) a += one; else bb += one;
        }
        sA[tid] = a; sB[tid] = bb;
        __syncthreads();
        for (int off = 1; off < 1024; off <<= 1){
            unsigned long long ta = 0, tb = 0;
            if (tid >= off){ ta = sA[tid - off]; tb = sB[tid - off]; }
            __syncthreads();
            sA[tid] += ta; sB[tid] += tb;
            __syncthreads();
        }
        const unsigned long long iA = sA[tid],  iB = sB[tid];
        const unsigned long long tA = sA[1023], tB = sB[1023];

        int cnt[NEXP], pad[NEXP], off_e[NEXP], tc[NEXP + 1];
        tc[0] = 0;
        int o = 0;
        #pragma unroll
        for (int e = 0; e < NEXP; e++){
            unsigned long long src = (e < 4) ? tA : tB;
            cnt[e] = (int)((src >> (16 * (e & 3))) & 0xffffull);
            pad[e] = (cnt[e] + 127) & ~127;
            off_e[e] = o; o += pad[e];
            tc[e + 1] = tc[e] + (pad[e] >> 7);
        }
        const int nrows = o, nt = tc[NEXP];

        if (tid == 0) meta[16] = nt;
        if (tid < NEXP) meta[17 + tid] = off_e[tid];
        if (tid < nt){
            int e = 0;
            while (tid >= tc[e + 1]) e++;
            map[tid] = make_int2(e, off_e[e] + (tid - tc[e]) * 128);
        }

        int run[NEXP];
        #pragma unroll
        for (int e = 0; e < NEXP; e++){
            unsigned long long isrc = (e < 4) ? iA : iB;
            unsigned long long csrc = (e < 4) ? a  : bb;
            int incl = (int)((isrc >> (16 * (e & 3))) & 0xffffull);
            int ce   = (int)((csrc >> (16 * (e & 3))) & 0xffffull);
            run[e] = off_e[e] + incl - ce;
        }
        #pragma unroll
        for (int i = 0; i < 16; i++){
            int e = mye[i];
            int gg = run[e]++;
            list[gg] = (base + i) >> 1;      // row -> token (K=2)
            slot2row[base + i] = gg;         // slot -> row (combine)
        }
        for (int p = tid; p < nrows; p += 1024){
            #pragma unroll
            for (int e = 0; e < NEXP; e++){
                if (p >= off_e[e] + cnt[e] && p < off_e[e] + pad[e]) list[p] = 0;
            }
        }
    } else if (b < 1 + NB_CAST){
        // ---- cast x -> bf16, 8 elems/thread ----
        int i = (b - 1) * 1024 + tid;          // < 524288
        const float4* s = (const float4*)x;
        float4 va = s[2 * i];
        float4 vb = s[2 * i + 1];
        u16x8 ov;
        ov[0] = f2bf(va.x); ov[1] = f2bf(va.y); ov[2] = f2bf(va.z); ov[3] = f2bf(va.w);
        ov[4] = f2bf(vb.x); ov[5] = f2bf(vb.y); ov[6] = f2bf(vb.z); ov[7] = f2bf(vb.w);
        *(u16x8*)(xbf + (size_t)i * 8) = ov;
    } else {
        // ---- transpose_cast: [E][R][C] fp32 -> [E][C][R] bf16, 32x32 tiles ----
        int blk = b - (1 + NB_CAST);
        const float* src; unsigned short* dst; int R, C, cpb_shift, cpb_mask;
        if (blk < NB_T){ src = W1; dst = w1t; R = DDIM; C = FDIM; cpb_shift = 5; cpb_mask = 31; }
        else           { src = W2; dst = w2t; R = FDIM; C = DDIM; cpb_shift = 4; cpb_mask = 15; blk -= NB_T; }
        int e   = blk >> 9;            // 512 tiles per expert
        int rem = blk & 511;
        int rb  = rem >> cpb_shift, cb = rem & cpb_mask;
        int r0 = rb * 32, c0 = cb * 32;
        int tx = tid & 31, ty = tid >> 5;   // (32,32)
        const float* sf = src + (size_t)e * R * C;
        unsigned short* d = dst + (size_t)e * R * C;
        tile[ty][tx] = f2bf(sf[(size_t)(r0 + ty) * C + c0 + tx]);
        __syncthreads();
        d[(size_t)(c0 + ty) * R + r0 + tx] = tile[tx][ty];
    }
}

// ---- GEMM1: h[row, F] = gelu(xbf[tok(row)] @ W1t[e]^T + b1[e]) ----
// R2/R7-proven inner loop: 128x128 tile, BK=64, split K-panels [ks=2][128][32]
// (64 B row stride), single-buffered 32 KB, plain __syncthreads.
// NEW (R10): epilogue stages acc->LDS (XOR-swizzled, write-conflict-free) and
// stores u16x8 coalesced (256 B segments) instead of 64 scattered 2 B stores.
__global__ __launch_bounds__(256, 2) void gemm1_kernel(
    const unsigned short* __restrict__ x,
    const unsigned short* __restrict__ w1t,
    const float* __restrict__ b1,
    const int* __restrict__ meta,
    const int2* __restrict__ map,
    const int* __restrict__ list,
    unsigned short* __restrict__ h)
{
    const int ntiles = meta[16];
    const int nwg = ntiles * (FDIM / 128);            // 8 n-tiles per row-tile
    int id = blockIdx.y * gridDim.x + blockIdx.x;
    if (id >= nwg) return;
    // bijective XCD swizzle (m204 variant)
    int q = nwg >> 3, r = nwg & 7;
    int xcd = id & 7, rank = id >> 3;
    int swz = (xcd < r) ? (xcd * (q + 1) + rank)
                        : (r * (q + 1) + (xcd - r) * q + rank);
    const int tile = swz >> 3;                        // / (FDIM/128)
    const int n0 = (swz & 7) * 128;
    int2 em = map[tile];
    const int e = em.x, grow0 = em.y;

    __shared__ __align__(16) unsigned short smem[16384];   // 32 KB: As|Bs, then epilogue stage
    unsigned short* As = smem;            // [ks=2][128][32] = 8192 u16
    unsigned short* Bs = smem + 8192;

    const int tid  = threadIdx.x;
    const int wave = tid >> 6;
    const int lane = tid & 63;
    const int rl   = lane >> 2;         // row within 16-row group
    const int kq   = lane & 3;          // 16B k-octet within 32-elem panel

    const int row0 = wave * 16 + rl;        // 0..63
    const int row1 = 64 + wave * 16 + rl;   // 64..127

    const unsigned short* pA0 = x + (size_t)list[grow0 + row0] * DDIM + kq * 8;
    const unsigned short* pA1 = x + (size_t)list[grow0 + row1] * DDIM + kq * 8;
    const unsigned short* pB0 = w1t + ((size_t)e * FDIM + n0 + row0) * DDIM + kq * 8;
    const unsigned short* pB1 = w1t + ((size_t)e * FDIM + n0 + row1) * DDIM + kq * 8;

    char* lA = (char*)As + wave * 1024;
    char* lB = (char*)Bs + wave * 1024;

    const int quad = lane >> 4, lrow = lane & 15;
    const int wr = (wave >> 1) * 64;    // wave row offset
    const int wc = (wave & 1) * 64;     // wave col offset

    f32x4 acc[4][4];
    #pragma unroll
    for (int i = 0; i < 4; i++)
        #pragma unroll
        for (int j = 0; j < 4; j++) acc[i][j] = (f32x4)0.0f;

    for (int kk = 0; kk < DDIM; kk += 64){
        __syncthreads();
        GL2LDS(pA0 + kk,      lA);              // ks=0, rows 0..63
        GL2LDS(pA1 + kk,      lA + 4096);       // ks=0, rows 64..127
        GL2LDS(pA0 + kk + 32, lA + 8192);       // ks=1, rows 0..63
        GL2LDS(pA1 + kk + 32, lA + 12288);      // ks=1, rows 64..127
        GL2LDS(pB0 + kk,      lB);
        GL2LDS(pB1 + kk,      lB + 4096);
        GL2LDS(pB0 + kk + 32, lB + 8192);
        GL2LDS(pB1 + kk + 32, lB + 12288);
        __syncthreads();
        bf16x8 a[4][2], b[4][2];
        #pragma unroll
        for (int i = 0; i < 4; i++){
            #pragma unroll
            for (int ks = 0; ks < 2; ks++){
                a[i][ks] = *(const bf16x8*)&As[ks * 4096 + (wr + i * 16 + lrow) * 32 + quad * 8];
                b[i][ks] = *(const bf16x8*)&Bs[ks * 4096 + (wc + i * 16 + lrow) * 32 + quad * 8];
            }
        }
        #pragma unroll
        for (int i = 0; i < 4; i++){
            #pragma unroll
            for (int j = 0; j < 4; j++){
                acc[i][j] = __builtin_amdgcn_mfma_f32_16x16x32_bf16(a[i][0], b[j][0], acc[i][j], 0, 0, 0);
                acc[i][j] = __builtin_amdgcn_mfma_f32_16x16x32_bf16(a[i][1], b[j][1], acc[i][j], 0, 0, 0);
            }
        }
    }

    // ---- epilogue: gelu+bias -> LDS (swizzled) -> coalesced u16x8 stores ----
    __syncthreads();    // all waves done reading As/Bs
    #pragma unroll
    for (int j = 0; j < 4; j++){
        int C = wc + j * 16 + lrow;
        float bias = b1[e * FDIM + n0 + C];
        #pragma unroll
        for (int i = 0; i < 4; i++){
            #pragma unroll
            for (int rr = 0; rr < 4; rr++){
                int R = wr + i * 16 + quad * 4 + rr;
                smem[R * 128 + (C ^ (((R >> 2) & 7) << 4))] =
                    f2bf(gelu_fast(acc[i][j][rr] + bias));
            }
        }
    }
    __syncthreads();
    #pragma unroll
    for (int p = 0; p < 8; p++){
        int idx = p * 2048 + tid * 8;
        int R = idx >> 7, C = idx & 127;          // C multiple of 8
        u16x8 v = *(const u16x8*)&smem[R * 128 + (C ^ (((R >> 2) & 7) << 4))];
        *(u16x8*)&h[(size_t)(grow0 + R) * FDIM + n0 + C] = v;
    }
}

// ---- GEMM2: y[row, D] = h[row] @ W2t[e]^T + b2[e] ----
// R7-proven 128x128 structure, K=FDIM, W2t layout [E][D][F] bf16.
// Same R10 coalesced epilogue.
__global__ __launch_bounds__(256, 2) void gemm2_kernel(
    const unsigned short* __restrict__ h,
    const unsigned short* __restrict__ w2t,
    const float* __restrict__ b2,
    const int* __restrict__ meta,
    const int2* __restrict__ map,
    unsigned short* __restrict__ y)
{
    const int ntiles = meta[16];
    const int nwg = ntiles * (DDIM / 128);            // 4 n-tiles per row-tile
    int id = blockIdx.y * gridDim.x + blockIdx.x;
    if (id >= nwg) return;
    int q = nwg >> 3, r = nwg & 7;
    int xcd = id & 7, rank = id >> 3;
    int swz = (xcd < r) ? (xcd * (q + 1) + rank)
                        : (r * (q + 1) + (xcd - r) * q + rank);
    const int tile = swz >> 2;                        // / (DDIM/128)
    const int n0 = (swz & 3) * 128;
    int2 em = map[tile];
    const int e = em.x, grow0 = em.y;

    __shared__ __align__(16) unsigned short smem[16384];   // 32 KB
    unsigned short* As = smem;
    unsigned short* Bs = smem + 8192;

    const int tid  = threadIdx.x;
    const int wave = tid >> 6;
    const int lane = tid & 63;
    const int rl   = lane >> 2;
    const int kq   = lane & 3;

    const int row0 = wave * 16 + rl;
    const int row1 = 64 + wave * 16 + rl;

    const unsigned short* pA0 = h + (size_t)(grow0 + row0) * FDIM + kq * 8;
    const unsigned short* pA1 = h + (size_t)(grow0 + row1) * FDIM + kq * 8;
    const unsigned short* pB0 = w2t + ((size_t)e * DDIM + n0 + row0) * FDIM + kq * 8;
    const unsigned short* pB1 = w2t + ((size_t)e * DDIM + n0 + row1) * FDIM + kq * 8;

    char* lA = (char*)As + wave * 1024;
    char* lB = (char*)Bs + wave * 1024;

    const int quad = lane >> 4, lrow = lane & 15;
    const int wr = (wave >> 1) * 64;
    const int wc = (wave & 1) * 64;

    f32x4 acc[4][4];
    #pragma unroll
    for (int i = 0; i < 4; i++)
        #pragma unroll
        for (int j = 0; j < 4; j++) acc[i][j] = (f32x4)0.0f;

    for (int kk = 0; kk < FDIM; kk += 64){
        __syncthreads();
        GL2LDS(pA0 + kk,      lA);
        GL2LDS(pA1 + kk,      lA + 4096);
        GL2LDS(pA0 + kk + 32, lA + 8192);
        GL2LDS(pA1 + kk + 32, lA + 12288);
        GL2LDS(pB0 + kk,      lB);
        GL2LDS(pB1 + kk,      lB + 4096);
        GL2LDS(pB0 + kk + 32, lB + 8192);
        GL2LDS(pB1 + kk + 32, lB + 12288);
        __syncthreads();
        bf16x8 a[4][2], b[4][2];
        #pragma unroll
        for (int i = 0; i < 4; i++){
            #pragma unroll
            for (int ks = 0; ks < 2; ks++){
                a[i][ks] = *(const bf16x8*)&As[ks * 4096 + (wr + i * 16 + lrow) * 32 + quad * 8];
                b[i][ks] = *(const bf16x8*)&Bs[ks * 4096 + (wc + i * 16 + lrow) * 32 + quad * 8];
            }
        }
        #pragma unroll
        for (int i = 0; i < 4; i++){
            #pragma unroll
            for (int j = 0; j < 4; j++){
                acc[i][j] = __builtin_amdgcn_mfma_f32_16x16x32_bf16(a[i][0], b[j][0], acc[i][j], 0, 0, 0);
                acc[i][j] = __builtin_amdgcn_mfma_f32_16x16x32_bf16(a[i][1], b[j][1], acc[i][j], 0, 0, 0);
            }
        }
    }

    // ---- epilogue: bias -> LDS (swizzled) -> coalesced u16x8 stores ----
    __syncthreads();
    #pragma unroll
    for (int j = 0; j < 4; j++){
        int C = wc + j * 16 + lrow;
        float bias = b2[e * DDIM + n0 + C];
        #pragma unroll
        for (int i = 0; i < 4; i++){
            #pragma unroll
            for (int rr = 0; rr < 4; rr++){
                int R = wr + i * 16 + quad * 4 + rr;
                smem[R * 128 + (C ^ (((R >> 2) & 7) << 4))] =
                    f2bf(acc[i][j][rr] + bias);
            }
        }
    }
    __syncthreads();
    #pragma unroll
    for (int p = 0; p < 8; p++){
        int idx = p * 2048 + tid * 8;
        int R = idx >> 7, C = idx & 127;
        u16x8 v = *(const u16x8*)&smem[R * 128 + (C ^ (((R >> 2) & 7) << 4))];
        *(u16x8*)&y[(size_t)(grow0 + R) * DDIM + n0 + C] = v;
    }
}

// out[t, :] = wk[2t] * y[row(2t), :] + wk[2t+1] * y[row(2t+1), :]
__global__ void combine_kernel(const unsigned short* __restrict__ y,
                               const int* __restrict__ slot2row,
                               const float* __restrict__ wk,
                               float* __restrict__ out){
    int g = blockIdx.x * blockDim.x + threadIdx.x;   // over T_TOK * DDIM / 4
    int t = g >> 7, seg = g & 127;
    int ra = slot2row[2 * t], rb = slot2row[2 * t + 1];
    float wa = wk[2 * t];
    float wb = wk[2 * t + 1];
    bf16x4 ya = *(const bf16x4*)(y + (size_t)ra * DDIM + seg * 4);
    bf16x4 yb = *(const bf16x4*)(y + (size_t)rb * DDIM + seg * 4);
    float4 o;
    o.x = wa * (float)ya[0] + wb * (float)yb[0];
    o.y = wa * (float)ya[1] + wb * (float)yb[1];
    o.z = wa * (float)ya[2] + wb * (float)yb[2];
    o.w = wa * (float)ya[3] + wb * (float)yb[3];
    *(float4*)(out + (size_t)t * DDIM + seg * 4) = o;
}

extern "C" void kernel_launch(void* const* d_in, const int* in_sizes, int n_in,
                              void* d_out, int out_size, void* d_ws, size_t ws_size,
                              hipStream_t stream){
    const float* x   = (const float*)d_in[0];
    const int*   idx = (const int*)d_in[1];
    const float* wk  = (const float*)d_in[2];
    const float* W1  = (const float*)d_in[3];
    const float* b1  = (const float*)d_in[4];
    const float* W2  = (const float*)d_in[5];
    const float* b2  = (const float*)d_in[6];
    float* out = (float*)d_out;

    char* ws = (char*)d_ws;
    int*   meta     = (int*)ws;                               // 512 B
    int2*  map      = (int2*)(ws + 512);                      // up to 136*8 B
    int*   list     = (int*)(ws + 4096);                      // 69,632 B (row->token)
    int*   slot2row = (int*)(ws + 81920);                     // 65,536 B (slot->row)
    unsigned short* xbf = (unsigned short*)(ws + 262144);     // 8,388,608 B [T][D]
    unsigned short* w1t = (unsigned short*)(ws + 8650752);    // 8,388,608 B [E][F][D]
    unsigned short* w2t = (unsigned short*)(ws + 17039360);   // 8,388,608 B [E][D][F]
    unsigned short* h   = (unsigned short*)(ws + 25427968);   // 35,651,584 B [MAX_ROWS][F]
    unsigned short* y   = (unsigned short*)(ws + 61079552);   // 17,825,792 B [MAX_ROWS][D]
    if (ws_size < 78905344u) return;   // tripwire -> zero output signature

    prep_kernel<<<PREP_BLOCKS, 1024, 0, stream>>>(
        x, idx, W1, W2, xbf, w1t, w2t, meta, map, list, slot2row);

    gemm1_kernel<<<dim3(FDIM / 128, MAX_T128), 256, 0, stream>>>(
        xbf, w1t, b1, meta, map, list, h);

    gemm2_kernel<<<dim3(DDIM / 128, MAX_T128), 256, 0, stream>>>(
        h, w2t, b2, meta, map, y);

    combine_kernel<<<(T_TOK * DDIM / 4) / 256, 256, 0, stream>>>(y, slot2row, wk, out);
}